// Round 1
// baseline (329.175 us; speedup 1.0000x reference)
//
#include <hip/hip_runtime.h>
#include <stdint.h>

// MoleculeMultiHeadSelfAttention on MI355X (gfx950), bf16-MFMA design.
// B=2048, N=50, C=256, H=8, D=32.
// Pipeline:
//   cast_pad x6 : Wq,Wk -> wqk[512][256]bf16 ; Wa,Wm -> [416][64]bf16 (zero-pad);
//                 adj,matrix -> [102416][64]bf16 (zero-pad)
//   proj_kernel : q,k = x @ [Wq;Wk]^T + b  (MFMA 64x64 tiles) -> ws bf16 [B*H][50][32]
//   attn_kernel : per (b,h), 1 wave: S^T = K·Q^T (swapped so softmax-over-m is
//                 lane-group-local), same for adj/matrix transforms, mix with
//                 softmax(lambdas), PV via LDS round-trip. Output f32.
// ws requirement ~126 MiB.

typedef __attribute__((ext_vector_type(8))) short short8;
typedef __attribute__((ext_vector_type(4))) float f32x4;

__device__ __forceinline__ unsigned short f2bf(float f) {
  unsigned int u = __float_as_uint(f);
  u = (u + 0x7FFFu + ((u >> 16) & 1u)) >> 16;   // RNE; inputs are finite
  return (unsigned short)u;
}

// ---------- cast f32 -> bf16 with zero padding into [dstR][1<<SH] ----------
template<int SH>
__global__ void cast_pad(const float* __restrict__ src, unsigned short* __restrict__ dst,
                         int srcR, int srcC, int total) {
  int stride = gridDim.x * blockDim.x;
  for (int idx = blockIdx.x * blockDim.x + threadIdx.x; idx < total; idx += stride) {
    int r = idx >> SH;
    int c = idx & ((1 << SH) - 1);
    float v = 0.f;
    if (r < srcR && c < srcC) v = src[(size_t)r * srcC + c];
    dst[idx] = f2bf(v);
  }
}

// ---------- projection GEMM: [102400 x 256] @ [512 x 256]^T -> q,k bf16 ----------
// tiles: 64(M) x 64(N), K=256 staged fully in LDS. 4 waves, wave w = 16 M-rows.
// LDS rows 512B, XOR-swizzled (byte ^= (row&7)<<4) for conflict-free ds_read_b128.
__global__ __launch_bounds__(256) void proj_kernel(
    const float* __restrict__ x, const unsigned short* __restrict__ wqk,
    const float* __restrict__ bq, const float* __restrict__ bk,
    unsigned short* __restrict__ qws, unsigned short* __restrict__ kws) {
  __shared__ char xa[64 * 512];
  __shared__ char wb[64 * 512];
  const int bidM = blockIdx.x % 1600;
  const int bidN = blockIdx.x / 1600;
  const int m0 = bidM * 64, n0 = bidN * 64;
  const int tid = threadIdx.x;

  // stage x tile: 64 rows x 256 f32 -> bf16
#pragma unroll
  for (int t = 0; t < 16; ++t) {
    int idx = tid + t * 256;
    int r = idx >> 6, c4 = idx & 63;
    float4 v = *(const float4*)(x + (size_t)(m0 + r) * 256 + c4 * 4);
    unsigned long long pk = (unsigned long long)f2bf(v.x)
                          | ((unsigned long long)f2bf(v.y) << 16)
                          | ((unsigned long long)f2bf(v.z) << 32)
                          | ((unsigned long long)f2bf(v.w) << 48);
    int byte = (r * 512 + c4 * 8) ^ ((r & 7) << 4);
    *(unsigned long long*)(xa + byte) = pk;
  }
  // stage W tile: 64 rows x 256 bf16 (already cast)
#pragma unroll
  for (int t = 0; t < 8; ++t) {
    int idx = tid + t * 256;
    int r = idx >> 5, c8 = idx & 31;
    short8 v = *(const short8*)(wqk + (size_t)(n0 + r) * 256 + c8 * 8);
    int byte = (r * 512 + c8 * 16) ^ ((r & 7) << 4);
    *(short8*)(wb + byte) = v;
  }
  __syncthreads();

  const int w = tid >> 6, l = tid & 63, lo = l & 15, g = l >> 4;
  f32x4 acc[4];
#pragma unroll
  for (int tj = 0; tj < 4; ++tj) acc[tj] = (f32x4){0.f, 0.f, 0.f, 0.f};

#pragma unroll
  for (int ks = 0; ks < 8; ++ks) {
    int ra = 16 * w + lo;
    short8 a = *(const short8*)(xa + ((ra * 512 + ks * 64 + g * 16) ^ ((ra & 7) << 4)));
#pragma unroll
    for (int tj = 0; tj < 4; ++tj) {
      int rb = 16 * tj + lo;
      short8 bb = *(const short8*)(wb + ((rb * 512 + ks * 64 + g * 16) ^ ((rb & 7) << 4)));
      acc[tj] = __builtin_amdgcn_mfma_f32_16x16x32_bf16(a, bb, acc[tj], 0, 0, 0);
    }
  }
  // epilogue: D row = m (x rows), col = j (W rows). C/D: col=l&15, row=(l>>4)*4+i.
#pragma unroll
  for (int tj = 0; tj < 4; ++tj) {
    int j = n0 + 16 * tj + lo;
    int jj = j & 255;
    float bias = (j < 256) ? bq[jj] : bk[jj];
    unsigned short* dst = (j < 256) ? qws : kws;
    int hh = jj >> 5, d = jj & 31;
#pragma unroll
    for (int i = 0; i < 4; ++i) {
      int m = m0 + 16 * w + 4 * g + i;
      int b = m / 50;
      int n = m - b * 50;
      size_t off = (((size_t)b * 8 + hh) * 50 + n) * 32 + d;
      dst[off] = f2bf(acc[tj][i] + bias);
    }
  }
}

// ---------- fused attention, one wave per (b,h) ----------
// Computes D = U · V^T with U rows on first operand's (l&15), V rows on second's.
// All three score matrices computed TRANSPOSED (rows = reduction axis m), so
// softmax over m = 16 in-lane values + shfl_xor(16,32) across the 4 lane-groups.

__device__ __forceinline__ void softmax_acc(f32x4 (&S)[4], const float (&bias)[4][4],
                                            float scale, float lamv,
                                            float (&pmix)[4][4][4], int tj, int g) {
  float mx = -3.0e38f;
#pragma unroll
  for (int ti = 0; ti < 4; ++ti)
#pragma unroll
    for (int i = 0; i < 4; ++i) {
      int m = 16 * ti + 4 * g + i;
      float v = S[ti][i] * scale + bias[ti][i];
      if (m >= 50) v = -1.0e30f;   // mask padded rows
      S[ti][i] = v;
      mx = fmaxf(mx, v);
    }
  mx = fmaxf(mx, __shfl_xor(mx, 16));
  mx = fmaxf(mx, __shfl_xor(mx, 32));
  float sum = 0.f;
#pragma unroll
  for (int ti = 0; ti < 4; ++ti)
#pragma unroll
    for (int i = 0; i < 4; ++i) {
      float p = __expf(S[ti][i] - mx);
      S[ti][i] = p;
      sum += p;
    }
  sum += __shfl_xor(sum, 16);
  sum += __shfl_xor(sum, 32);
  float r = lamv / sum;
#pragma unroll
  for (int ti = 0; ti < 4; ++ti)
#pragma unroll
    for (int i = 0; i < 4; ++i)
      pmix[ti][tj][i] += S[ti][i] * r;
}

__device__ __forceinline__ void adj_phase(const unsigned short* __restrict__ aBase,  // W rows (64 wide)
                                          const unsigned short* __restrict__ bBase,  // adj rows (64 wide)
                                          const float* __restrict__ biasPtr,
                                          float lamv, float (&pmix)[4][4][4], int lo, int g) {
  short8 af[4][2];
#pragma unroll
  for (int ti = 0; ti < 4; ++ti)
#pragma unroll
    for (int ks = 0; ks < 2; ++ks)
      af[ti][ks] = *(const short8*)(aBase + (size_t)(lo + 16 * ti) * 64 + ks * 32 + g * 8);
  float bias[4][4];
#pragma unroll
  for (int ti = 0; ti < 4; ++ti)
#pragma unroll
    for (int i = 0; i < 4; ++i) {
      int mv = 16 * ti + 4 * g + i;
      bias[ti][i] = (mv < 50) ? biasPtr[mv] : 0.f;
    }
#pragma unroll
  for (int tj = 0; tj < 4; ++tj) {
    f32x4 S[4];
#pragma unroll
    for (int ti = 0; ti < 4; ++ti) S[ti] = (f32x4){0.f, 0.f, 0.f, 0.f};
#pragma unroll
    for (int ks = 0; ks < 2; ++ks) {
      short8 bf8 = *(const short8*)(bBase + (size_t)(lo + 16 * tj) * 64 + ks * 32 + g * 8);
#pragma unroll
      for (int ti = 0; ti < 4; ++ti)
        S[ti] = __builtin_amdgcn_mfma_f32_16x16x32_bf16(af[ti][ks], bf8, S[ti], 0, 0, 0);
    }
    softmax_acc(S, bias, 1.0f, lamv, pmix, tj, g);
  }
}

__global__ __launch_bounds__(64) void attn_kernel(
    const unsigned short* __restrict__ qws, const unsigned short* __restrict__ kws,
    const unsigned short* __restrict__ adjb, const unsigned short* __restrict__ matb,
    const unsigned short* __restrict__ wab, const unsigned short* __restrict__ wmb,
    const float* __restrict__ ba, const float* __restrict__ bm,
    const float* __restrict__ lambdas, float* __restrict__ out) {
  __shared__ unsigned short kT[32 * 72];   // V^T: [d][m], zero-padded m>=50
  __shared__ unsigned short P[64 * 72];    // mixed probs: [n][m] bf16
  const int bh = blockIdx.x;
  const int b = bh >> 3, h = bh & 7;
  const int l = threadIdx.x, lo = l & 15, g = l >> 4;

  // softmax(lambdas[h])
  float la = lambdas[h * 3 + 0], lb = lambdas[h * 3 + 1], lc = lambdas[h * 3 + 2];
  float lmx = fmaxf(la, fmaxf(lb, lc));
  float e0 = __expf(la - lmx), e1 = __expf(lb - lmx), e2 = __expf(lc - lmx);
  float einv = 1.f / (e0 + e1 + e2);
  float lam0 = e0 * einv, lam1 = e1 * einv, lam2 = e2 * einv;

  // stage kT (transposed V) with zeroed pad rows
  {
    int m = l;
    const unsigned short* kr = kws + ((size_t)bh * 50 + m) * 32;
#pragma unroll
    for (int ch = 0; ch < 4; ++ch) {
      short8 v = (short8){0, 0, 0, 0, 0, 0, 0, 0};
      if (m < 50) v = *(const short8*)(kr + ch * 8);
#pragma unroll
      for (int jj = 0; jj < 8; ++jj)
        kT[(ch * 8 + jj) * 72 + m] = (unsigned short)v[jj];
    }
  }
  __syncthreads();

  float pmix[4][4][4] = {};

  // Phase 1: attention. S^T = K·Q^T, scale = C^-0.5 = 1/16.
  {
    short8 af[4];
#pragma unroll
    for (int ti = 0; ti < 4; ++ti)
      af[ti] = *(const short8*)(kws + ((size_t)bh * 50 + lo + 16 * ti) * 32 + g * 8);
    float zb[4][4] = {};
#pragma unroll
    for (int tj = 0; tj < 4; ++tj) {
      short8 bq8 = *(const short8*)(qws + ((size_t)bh * 50 + lo + 16 * tj) * 32 + g * 8);
      f32x4 S[4];
#pragma unroll
      for (int ti = 0; ti < 4; ++ti) S[ti] = (f32x4){0.f, 0.f, 0.f, 0.f};
#pragma unroll
      for (int ti = 0; ti < 4; ++ti)
        S[ti] = __builtin_amdgcn_mfma_f32_16x16x32_bf16(af[ti], bq8, S[ti], 0, 0, 0);
      softmax_acc(S, zb, 0.0625f, lam0, pmix, tj, g);
    }
  }
  // Phase 2: adj transform.  S_adj^T = Wa_h · adj_b^T + ba
  adj_phase(wab + (size_t)h * 50 * 64, adjb + (size_t)b * 50 * 64, ba + h * 50, lam1, pmix, lo, g);
  // Phase 3: matrix transform.
  adj_phase(wmb + (size_t)h * 50 * 64, matb + (size_t)b * 50 * 64, bm + h * 50, lam2, pmix, lo, g);

  // write P: lane holds P^T[m=16ti+4g+i][n=lo+16tj] -> store P[n][m] bf16
#pragma unroll
  for (int tj = 0; tj < 4; ++tj) {
    int n = lo + 16 * tj;
#pragma unroll
    for (int ti = 0; ti < 4; ++ti) {
      uint2 pk;
      pk.x = (unsigned)f2bf(pmix[ti][tj][0]) | ((unsigned)f2bf(pmix[ti][tj][1]) << 16);
      pk.y = (unsigned)f2bf(pmix[ti][tj][2]) | ((unsigned)f2bf(pmix[ti][tj][3]) << 16);
      *(uint2*)(P + (size_t)n * 72 + 16 * ti + 4 * g) = pk;
    }
  }
  __syncthreads();

  // PV: O = P · V   (A = P rows n, B = V rows d via kT)
  f32x4 O[4][2];
#pragma unroll
  for (int ti = 0; ti < 4; ++ti)
#pragma unroll
    for (int tj = 0; tj < 2; ++tj) O[ti][tj] = (f32x4){0.f, 0.f, 0.f, 0.f};
#pragma unroll
  for (int ks = 0; ks < 2; ++ks) {
    short8 pa[4];
#pragma unroll
    for (int ti = 0; ti < 4; ++ti)
      pa[ti] = *(const short8*)(P + (size_t)(lo + 16 * ti) * 72 + ks * 32 + g * 8);
#pragma unroll
    for (int tj = 0; tj < 2; ++tj) {
      short8 vb = *(const short8*)(kT + (size_t)(lo + 16 * tj) * 72 + ks * 32 + g * 8);
#pragma unroll
      for (int ti = 0; ti < 4; ++ti)
        O[ti][tj] = __builtin_amdgcn_mfma_f32_16x16x32_bf16(pa[ti], vb, O[ti][tj], 0, 0, 0);
    }
  }
  // out[b][n][h*32 + d], f32
  float* ob = out + ((size_t)b * 50) * 256 + h * 32;
#pragma unroll
  for (int ti = 0; ti < 4; ++ti)
#pragma unroll
    for (int i = 0; i < 4; ++i) {
      int n = 16 * ti + 4 * g + i;
      if (n < 50) {
#pragma unroll
        for (int tj = 0; tj < 2; ++tj)
          ob[(size_t)n * 256 + 16 * tj + lo] = O[ti][tj][i];
      }
    }
}

extern "C" void kernel_launch(void* const* d_in, const int* in_sizes, int n_in,
                              void* d_out, int out_size, void* d_ws, size_t ws_size,
                              hipStream_t stream) {
  const float* x       = (const float*)d_in[0];
  const float* adj     = (const float*)d_in[1];
  const float* mat     = (const float*)d_in[2];
  const float* Wq      = (const float*)d_in[3];
  const float* bq      = (const float*)d_in[4];
  const float* Wk      = (const float*)d_in[5];
  const float* bk      = (const float*)d_in[6];
  const float* Wa      = (const float*)d_in[7];
  const float* ba      = (const float*)d_in[8];
  const float* Wm      = (const float*)d_in[9];
  const float* bm      = (const float*)d_in[10];
  const float* lambdas = (const float*)d_in[11];
  float* out = (float*)d_out;

  // ws layout (bytes, all 16B-aligned); total ~125.4 MiB
  char* ws = (char*)d_ws;
  unsigned short* wqk  = (unsigned short*)ws; ws += (size_t)512 * 256 * 2;
  unsigned short* wab  = (unsigned short*)ws; ws += (size_t)416 * 64 * 2;
  unsigned short* wmb  = (unsigned short*)ws; ws += (size_t)416 * 64 * 2;
  unsigned short* adjb = (unsigned short*)ws; ws += (size_t)102416 * 64 * 2;
  unsigned short* matb = (unsigned short*)ws; ws += (size_t)102416 * 64 * 2;
  unsigned short* qws  = (unsigned short*)ws; ws += (size_t)819264 * 32 * 2;
  unsigned short* kws  = (unsigned short*)ws; ws += (size_t)819264 * 32 * 2;

  cast_pad<8><<<256, 256, 0, stream>>>(Wq, wqk, 256, 256, 256 * 256);
  cast_pad<8><<<256, 256, 0, stream>>>(Wk, wqk + 256 * 256, 256, 256, 256 * 256);
  cast_pad<6><<<104, 256, 0, stream>>>(Wa, wab, 400, 50, 416 * 64);
  cast_pad<6><<<104, 256, 0, stream>>>(Wm, wmb, 400, 50, 416 * 64);
  cast_pad<6><<<2048, 256, 0, stream>>>(adj, adjb, 102400, 50, 102416 * 64);
  cast_pad<6><<<2048, 256, 0, stream>>>(mat, matb, 102400, 50, 102416 * 64);
  proj_kernel<<<12800, 256, 0, stream>>>(x, wqk, bq, bk, qws, kws);
  attn_kernel<<<16384, 64, 0, stream>>>(qws, kws, adjb, matb, wab, wmb, ba, bm, lambdas, out);
}

// Round 2
// 218.922 us; speedup vs baseline: 1.5036x; 1.5036x over previous
//
#include <hip/hip_runtime.h>
#include <stdint.h>

// MoleculeMultiHeadSelfAttention on MI355X (gfx950), bf16-MFMA design, round 2.
// B=2048, N=50, C=256, H=8, D=32.
//   castW   : Wq,Wk -> wqk[512][256] bf16
//   castS   : Wa,Wm -> [416][64] bf16 zero-padded
//   castA   : adj,matrix -> [102416][64] bf16 zero-padded (vectorized)
//   proj    : q,k = x @ [Wq;Wk]^T + b ; block stages x-tile once, loops 8 N-tiles
//   attn    : 4 independent waves/block, one (b,h) per wave, per-phase PV into O,
//             wave-private LDS (no __syncthreads), mask folded into bias.

typedef __attribute__((ext_vector_type(8))) short short8;
typedef __attribute__((ext_vector_type(4))) float f32x4;
typedef unsigned short u16;

__device__ __forceinline__ u16 f2bf(float f) {
  unsigned int u = __float_as_uint(f);
  u = (u + 0x7FFFu + ((u >> 16) & 1u)) >> 16;   // RNE; finite inputs
  return (u16)u;
}
__device__ __forceinline__ unsigned cvt_pk_bf16(float a, float b) {
  unsigned r;
  asm("v_cvt_pk_bf16_f32 %0, %1, %2" : "=v"(r) : "v"(a), "v"(b));
  return r;
}

// ---------------- casts ----------------
__global__ __launch_bounds__(256) void castW(const float* __restrict__ Wq,
                                             const float* __restrict__ Wk,
                                             u16* __restrict__ dst) {
  int idx8 = blockIdx.x * 256 + threadIdx.x;            // 16384 threads exact
  int r = idx8 >> 5, c = (idx8 & 31) * 8;
  const float* src = (r < 256) ? (Wq + (size_t)r * 256 + c)
                               : (Wk + (size_t)(r - 256) * 256 + c);
  float4 v0 = *(const float4*)(src);
  float4 v1 = *(const float4*)(src + 4);
  short8 o;
  o[0] = f2bf(v0.x); o[1] = f2bf(v0.y); o[2] = f2bf(v0.z); o[3] = f2bf(v0.w);
  o[4] = f2bf(v1.x); o[5] = f2bf(v1.y); o[6] = f2bf(v1.z); o[7] = f2bf(v1.w);
  *(short8*)(dst + (size_t)idx8 * 8) = o;
}

__global__ __launch_bounds__(256) void castS(const float* __restrict__ Wa,
                                             const float* __restrict__ Wm,
                                             u16* __restrict__ da, u16* __restrict__ dm) {
  int idx = blockIdx.x * 256 + threadIdx.x;             // 26624 threads exact
  int r = idx >> 6, c = idx & 63;
  float va = 0.f, vm = 0.f;
  if (r < 400 && c < 50) { va = Wa[r * 50 + c]; vm = Wm[r * 50 + c]; }
  da[idx] = f2bf(va); dm[idx] = f2bf(vm);
}

__global__ __launch_bounds__(256) void castA(const float* __restrict__ adj,
                                             const float* __restrict__ mat,
                                             u16* __restrict__ da, u16* __restrict__ dm) {
  const int total8 = (102416 * 64) / 8;                 // 819328
  int stride = gridDim.x * 256;
  for (int i8 = blockIdx.x * 256 + threadIdx.x; i8 < total8; i8 += stride) {
    int r = i8 >> 3, c = (i8 & 7) * 8;
    short8 oa = (short8){0,0,0,0,0,0,0,0};
    short8 om = (short8){0,0,0,0,0,0,0,0};
    if (r < 102400) {
      size_t base = (size_t)r * 50;
#pragma unroll
      for (int p = 0; p < 4; ++p) {
        int col = c + 2 * p;
        if (col < 50) {                                  // 50 even -> no straddle
          float2 va = *(const float2*)(adj + base + col);
          float2 vm = *(const float2*)(mat + base + col);
          oa[2*p] = f2bf(va.x); oa[2*p+1] = f2bf(va.y);
          om[2*p] = f2bf(vm.x); om[2*p+1] = f2bf(vm.y);
        }
      }
    }
    *(short8*)(da + (size_t)i8 * 8) = oa;
    *(short8*)(dm + (size_t)i8 * 8) = om;
  }
}

// ---------------- projection GEMM ----------------
// grid 1600; block stages x tile (64 x 256 -> bf16 LDS) once, loops 8 N-tiles.
__global__ __launch_bounds__(256) void proj_kernel(
    const float* __restrict__ x, const u16* __restrict__ wqk,
    const float* __restrict__ bq, const float* __restrict__ bk,
    u16* __restrict__ qws, u16* __restrict__ kws) {
  __shared__ char xa[64 * 512];
  __shared__ char wb[64 * 512];
  const int tid = threadIdx.x;
  const int m0 = blockIdx.x * 64;

  // stage x tile, f32 -> bf16, XOR-swizzled rows (512B)
#pragma unroll
  for (int t = 0; t < 16; ++t) {
    int idx = tid + t * 256;
    int r = idx >> 6, c4 = idx & 63;
    float4 v = *(const float4*)(x + (size_t)(m0 + r) * 256 + c4 * 4);
    unsigned long long pk = (unsigned long long)f2bf(v.x)
                          | ((unsigned long long)f2bf(v.y) << 16)
                          | ((unsigned long long)f2bf(v.z) << 32)
                          | ((unsigned long long)f2bf(v.w) << 48);
    int byte = (r * 512 + c4 * 8) ^ ((r & 7) << 4);
    *(unsigned long long*)(xa + byte) = pk;
  }
  __syncthreads();

  const int w = tid >> 6, l = tid & 63, lo = l & 15, g = l >> 4;
  // hoist A-fragments (this wave's 16 x-rows), reused across all 8 N-tiles
  short8 a[8];
  const int ra = 16 * w + lo;
#pragma unroll
  for (int ks = 0; ks < 8; ++ks)
    a[ks] = *(const short8*)(xa + ((ra * 512 + ks * 64 + g * 16) ^ ((ra & 7) << 4)));
  // store bases: off = b*12800 + hh*1600 + n*32 + d
  size_t mb[4];
#pragma unroll
  for (int i = 0; i < 4; ++i) {
    int m = m0 + 16 * w + 4 * g + i;
    int b = m / 50;
    int n = m - 50 * b;
    mb[i] = (size_t)b * 12800 + (size_t)n * 32;
  }

  for (int nt = 0; nt < 8; ++nt) {
    __syncthreads();   // previous iter's wb reads done
#pragma unroll
    for (int t = 0; t < 8; ++t) {
      int idx = tid + t * 256;
      int r = idx >> 5, c8 = idx & 31;
      short8 v = *(const short8*)(wqk + (size_t)(nt * 64 + r) * 256 + c8 * 8);
      int byte = (r * 512 + c8 * 16) ^ ((r & 7) << 4);
      *(short8*)(wb + byte) = v;
    }
    __syncthreads();   // wb ready

    f32x4 acc[4];
#pragma unroll
    for (int tj = 0; tj < 4; ++tj) acc[tj] = (f32x4){0.f, 0.f, 0.f, 0.f};
#pragma unroll
    for (int ks = 0; ks < 8; ++ks) {
#pragma unroll
      for (int tj = 0; tj < 4; ++tj) {
        int rb = 16 * tj + lo;
        short8 bb = *(const short8*)(wb + ((rb * 512 + ks * 64 + g * 16) ^ ((rb & 7) << 4)));
        acc[tj] = __builtin_amdgcn_mfma_f32_16x16x32_bf16(a[ks], bb, acc[tj], 0, 0, 0);
      }
    }
    // epilogue
    const int n0 = nt * 64;
#pragma unroll
    for (int tj = 0; tj < 4; ++tj) {
      int j = n0 + 16 * tj + lo;
      int jj = j & 255;
      float bias = (j < 256) ? bq[jj] : bk[jj];
      u16* dst = (j < 256) ? qws : kws;
      int hh = jj >> 5, d = jj & 31;
#pragma unroll
      for (int i = 0; i < 4; ++i)
        dst[mb[i] + (size_t)hh * 1600 + d] = f2bf(acc[tj][i] + bias);
    }
  }
}

// ---------------- fused attention ----------------
// One wave per (b,h); 4 waves/block, wave-private LDS (9216B), no __syncthreads.

__device__ __forceinline__ void lds_fence() {
  asm volatile("s_waitcnt lgkmcnt(0)" ::: "memory");
  __builtin_amdgcn_sched_barrier(0);
}

__device__ __forceinline__ void softmax_store(f32x4 (&S)[4], const float (&bias)[4][4],
                                              float scale, float lam,
                                              u16* sh, int tj, int lo, int g) {
  float mx = -3.0e38f;
#pragma unroll
  for (int ti = 0; ti < 4; ++ti)
#pragma unroll
    for (int i = 0; i < 4; ++i) {
      float v = S[ti][i] * scale + bias[ti][i];   // bias = -1e30 masks m>=50
      S[ti][i] = v;
      mx = fmaxf(mx, v);
    }
  mx = fmaxf(mx, __shfl_xor(mx, 16));
  mx = fmaxf(mx, __shfl_xor(mx, 32));
  float sum = 0.f;
#pragma unroll
  for (int ti = 0; ti < 4; ++ti)
#pragma unroll
    for (int i = 0; i < 4; ++i) {
      float p = __expf(S[ti][i] - mx);
      S[ti][i] = p;
      sum += p;
    }
  sum += __shfl_xor(sum, 16);
  sum += __shfl_xor(sum, 32);
  float r = lam * __builtin_amdgcn_rcpf(sum);
  const int n = lo + 16 * tj;
#pragma unroll
  for (int ti = 0; ti < 4; ++ti) {
    uint2 pk;
    pk.x = cvt_pk_bf16(S[ti][0] * r, S[ti][1] * r);
    pk.y = cvt_pk_bf16(S[ti][2] * r, S[ti][3] * r);
    *(uint2*)(sh + n * 72 + 16 * ti + 4 * g) = pk;   // 8B-aligned
  }
}

__device__ __forceinline__ void pv_accum(const u16* sh, const short8 (&vb)[2][2],
                                         f32x4 (&O)[4][2], int lo, int g) {
  lds_fence();   // all lanes' P writes visible
#pragma unroll
  for (int ks = 0; ks < 2; ++ks) {
    short8 pa[4];
#pragma unroll
    for (int ti = 0; ti < 4; ++ti)
      pa[ti] = *(const short8*)(sh + (lo + 16 * ti) * 72 + ks * 32 + g * 8);
#pragma unroll
    for (int tjv = 0; tjv < 2; ++tjv)
#pragma unroll
      for (int ti = 0; ti < 4; ++ti)
        O[ti][tjv] = __builtin_amdgcn_mfma_f32_16x16x32_bf16(pa[ti], vb[tjv][ks], O[ti][tjv], 0, 0, 0);
  }
}

__device__ __forceinline__ void adj_phase(const u16* __restrict__ aBase,
                                          const u16* __restrict__ bBase,
                                          const float* __restrict__ biasPtr,
                                          float lam, u16* sh, const short8 (&vb)[2][2],
                                          f32x4 (&O)[4][2], int lo, int g) {
  short8 af[4][2];
#pragma unroll
  for (int ti = 0; ti < 4; ++ti)
#pragma unroll
    for (int ks = 0; ks < 2; ++ks)
      af[ti][ks] = *(const short8*)(aBase + (size_t)(lo + 16 * ti) * 64 + ks * 32 + g * 8);
  float bias[4][4];
#pragma unroll
  for (int ti = 0; ti < 4; ++ti)
#pragma unroll
    for (int i = 0; i < 4; ++i) {
      int m = 16 * ti + 4 * g + i;
      bias[ti][i] = (m < 50) ? biasPtr[m] : -1.0e30f;
    }
#pragma unroll
  for (int tj = 0; tj < 4; ++tj) {
    f32x4 S[4];
#pragma unroll
    for (int ti = 0; ti < 4; ++ti) S[ti] = (f32x4){0.f, 0.f, 0.f, 0.f};
#pragma unroll
    for (int ks = 0; ks < 2; ++ks) {
      short8 bf8 = *(const short8*)(bBase + (size_t)(lo + 16 * tj) * 64 + ks * 32 + g * 8);
#pragma unroll
      for (int ti = 0; ti < 4; ++ti)
        S[ti] = __builtin_amdgcn_mfma_f32_16x16x32_bf16(af[ti][ks], bf8, S[ti], 0, 0, 0);
    }
    softmax_store(S, bias, 1.0f, lam, sh, tj, lo, g);
  }
  pv_accum(sh, vb, O, lo, g);
}

__global__ __launch_bounds__(256) void attn_kernel(
    const u16* __restrict__ qws, const u16* __restrict__ kws,
    const u16* __restrict__ adjb, const u16* __restrict__ matb,
    const u16* __restrict__ wab, const u16* __restrict__ wmb,
    const float* __restrict__ ba, const float* __restrict__ bm,
    const float* __restrict__ lambdas, float* __restrict__ out) {
  __shared__ u16 smem[4][4608];           // per-wave 9216B: kT[32][72] then P[64][72]
  const int tid = threadIdx.x;
  const int w = tid >> 6, l = tid & 63, lo = l & 15, g = l >> 4;
  const int bh = blockIdx.x * 4 + w;
  const int b = bh >> 3, h = bh & 7;
  u16* sh = smem[w];

  // softmax(lambdas[h])
  float la = lambdas[h * 3 + 0], lb = lambdas[h * 3 + 1], lc = lambdas[h * 3 + 2];
  float lmx = fmaxf(la, fmaxf(lb, lc));
  float e0 = __expf(la - lmx), e1 = __expf(lb - lmx), e2 = __expf(lc - lmx);
  float einv = 1.f / (e0 + e1 + e2);
  float lam0 = e0 * einv, lam1 = e1 * einv, lam2 = e2 * einv;

  // stage V^T = K^T into sh as [32 d][72 m], zero pad m>=50
  {
    const u16* kr = kws + ((size_t)bh * 50 + l) * 32;
#pragma unroll
    for (int ch = 0; ch < 4; ++ch) {
      short8 v = (short8){0, 0, 0, 0, 0, 0, 0, 0};
      if (l < 50) v = *(const short8*)(kr + ch * 8);
#pragma unroll
      for (int jj = 0; jj < 8; ++jj)
        sh[(ch * 8 + jj) * 72 + l] = (u16)v[jj];
    }
  }
  lds_fence();
  // hoist V^T fragments to registers (kT area is then reused as P)
  short8 vb[2][2];
#pragma unroll
  for (int tjv = 0; tjv < 2; ++tjv)
#pragma unroll
    for (int ks = 0; ks < 2; ++ks)
      vb[tjv][ks] = *(const short8*)(sh + (lo + 16 * tjv) * 72 + ks * 32 + g * 8);

  f32x4 O[4][2];
#pragma unroll
  for (int ti = 0; ti < 4; ++ti)
#pragma unroll
    for (int tjv = 0; tjv < 2; ++tjv) O[ti][tjv] = (f32x4){0.f, 0.f, 0.f, 0.f};

  // ---- phase 1: attention  S^T = K·Q^T, scale C^-0.5 = 1/16 ----
  {
    short8 af[4];
#pragma unroll
    for (int ti = 0; ti < 4; ++ti)
      af[ti] = *(const short8*)(kws + ((size_t)bh * 50 + lo + 16 * ti) * 32 + g * 8);
    float bias[4][4];
#pragma unroll
    for (int ti = 0; ti < 4; ++ti)
#pragma unroll
      for (int i = 0; i < 4; ++i)
        bias[ti][i] = (16 * ti + 4 * g + i < 50) ? 0.f : -1.0e30f;
#pragma unroll
    for (int tj = 0; tj < 4; ++tj) {
      short8 qf = *(const short8*)(qws + ((size_t)bh * 50 + lo + 16 * tj) * 32 + g * 8);
      f32x4 S[4];
#pragma unroll
      for (int ti = 0; ti < 4; ++ti) S[ti] = (f32x4){0.f, 0.f, 0.f, 0.f};
#pragma unroll
      for (int ti = 0; ti < 4; ++ti)
        S[ti] = __builtin_amdgcn_mfma_f32_16x16x32_bf16(af[ti], qf, S[ti], 0, 0, 0);
      softmax_store(S, bias, 0.0625f, lam0, sh, tj, lo, g);
    }
    pv_accum(sh, vb, O, lo, g);
  }
  // ---- phase 2 & 3: adj / matrix transforms ----
  adj_phase(wab + (size_t)h * 50 * 64, adjb + (size_t)b * 50 * 64, ba + h * 50,
            lam1, sh, vb, O, lo, g);
  adj_phase(wmb + (size_t)h * 50 * 64, matb + (size_t)b * 50 * 64, bm + h * 50,
            lam2, sh, vb, O, lo, g);

  // write out[b][n][h*32+d], f32; D rows = n, cols = d
  float* ob = out + ((size_t)b * 50) * 256 + h * 32;
#pragma unroll
  for (int ti = 0; ti < 4; ++ti)
#pragma unroll
    for (int i = 0; i < 4; ++i) {
      int n = 16 * ti + 4 * g + i;
      if (n < 50) {
#pragma unroll
        for (int tjv = 0; tjv < 2; ++tjv)
          ob[(size_t)n * 256 + 16 * tjv + lo] = O[ti][tjv][i];
      }
    }
}

extern "C" void kernel_launch(void* const* d_in, const int* in_sizes, int n_in,
                              void* d_out, int out_size, void* d_ws, size_t ws_size,
                              hipStream_t stream) {
  const float* x       = (const float*)d_in[0];
  const float* adj     = (const float*)d_in[1];
  const float* mat     = (const float*)d_in[2];
  const float* Wq      = (const float*)d_in[3];
  const float* bq      = (const float*)d_in[4];
  const float* Wk      = (const float*)d_in[5];
  const float* bk      = (const float*)d_in[6];
  const float* Wa      = (const float*)d_in[7];
  const float* ba      = (const float*)d_in[8];
  const float* Wm      = (const float*)d_in[9];
  const float* bm      = (const float*)d_in[10];
  const float* lambdas = (const float*)d_in[11];
  float* out = (float*)d_out;

  char* ws = (char*)d_ws;
  u16* wqk  = (u16*)ws; ws += (size_t)512 * 256 * 2;
  u16* wab  = (u16*)ws; ws += (size_t)416 * 64 * 2;
  u16* wmb  = (u16*)ws; ws += (size_t)416 * 64 * 2;
  u16* adjb = (u16*)ws; ws += (size_t)102416 * 64 * 2;
  u16* matb = (u16*)ws; ws += (size_t)102416 * 64 * 2;
  u16* qws  = (u16*)ws; ws += (size_t)819264 * 32 * 2;   // 16384*50 + 64 slack rows
  u16* kws  = (u16*)ws; ws += (size_t)819264 * 32 * 2;

  castW<<<64, 256, 0, stream>>>(Wq, Wk, wqk);
  castS<<<104, 256, 0, stream>>>(Wa, Wm, wab, wmb);
  castA<<<2048, 256, 0, stream>>>(adj, mat, adjb, matb);
  proj_kernel<<<1600, 256, 0, stream>>>(x, wqk, bq, bk, qws, kws);
  attn_kernel<<<4096, 256, 0, stream>>>(qws, kws, adjb, matb, wab, wmb, ba, bm, lambdas, out);
}

// Round 3
// 203.862 us; speedup vs baseline: 1.6147x; 1.0739x over previous
//
#include <hip/hip_runtime.h>
#include <stdint.h>

// MoleculeMultiHeadSelfAttention on MI355X (gfx950), round 3.
// B=2048, N=50, C=256, H=8, D=32.
//   cast_all : adj,matrix -> bf16 [102416][64]; Wq,Wk -> wqk[512][256];
//              Wa,Wm -> [416][64]; zero q/k slack rows. One launch.
//   proj     : q,k = x @ [Wq;Wk]^T + b -> bf16 [b][h][50][32] (+64 slack rows)
//   attn     : 1 wave per (b,h), 4 waves/block. Per-tj fused softmax+PV with
//              16-row double-buffered P in LDS (4608B/wave). No max-sub
//              (scores tiny), exp2 with folded log2e, tree-sum.

typedef __attribute__((ext_vector_type(8))) short short8;
typedef __attribute__((ext_vector_type(4))) float f32x4;
typedef unsigned short u16;

#define L2E 1.4426950408889634f

__device__ __forceinline__ u16 f2bf(float f) {
  unsigned int u = __float_as_uint(f);
  u = (u + 0x7FFFu + ((u >> 16) & 1u)) >> 16;   // RNE; finite inputs
  return (u16)u;
}
__device__ __forceinline__ unsigned cvt_pk_bf16(float a, float b) {
  unsigned r;
  asm("v_cvt_pk_bf16_f32 %0, %1, %2" : "=v"(r) : "v"(a), "v"(b));
  return r;
}
__device__ __forceinline__ float exp2_fast(float x) {
#if __has_builtin(__builtin_amdgcn_exp2f)
  return __builtin_amdgcn_exp2f(x);
#else
  return __expf(x * 0.6931471805599453f);   // exp(x ln2) = 2^x
#endif
}
__device__ __forceinline__ void lds_fence() {
  asm volatile("s_waitcnt lgkmcnt(0)" ::: "memory");
}

// ---------------- merged casts (one launch) ----------------
__global__ __launch_bounds__(256) void cast_all(
    const float* __restrict__ adj, const float* __restrict__ mat,
    const float* __restrict__ Wq, const float* __restrict__ Wk,
    const float* __restrict__ Wa, const float* __restrict__ Wm,
    u16* __restrict__ da, u16* __restrict__ dm, u16* __restrict__ wqk,
    u16* __restrict__ wab, u16* __restrict__ wmb,
    u16* __restrict__ qws, u16* __restrict__ kws) {
  const int blk = blockIdx.x, tid = threadIdx.x;
  if (blk < 2048) {
    // adj/matrix -> bf16 [102416][64], zero-padded
    const int total8 = (102416 * 64) / 8;
    for (int i8 = blk * 256 + tid; i8 < total8; i8 += 2048 * 256) {
      int r = i8 >> 3, c = (i8 & 7) * 8;
      short8 oa = (short8){0,0,0,0,0,0,0,0};
      short8 om = (short8){0,0,0,0,0,0,0,0};
      if (r < 102400) {
        size_t base = (size_t)r * 50;
#pragma unroll
        for (int p = 0; p < 4; ++p) {
          int col = c + 2 * p;
          if (col < 50) {
            float2 va = *(const float2*)(adj + base + col);
            float2 vm = *(const float2*)(mat + base + col);
            oa[2*p] = f2bf(va.x); oa[2*p+1] = f2bf(va.y);
            om[2*p] = f2bf(vm.x); om[2*p+1] = f2bf(vm.y);
          }
        }
      }
      *(short8*)(da + (size_t)i8 * 8) = oa;
      *(short8*)(dm + (size_t)i8 * 8) = om;
    }
  } else if (blk < 2112) {
    // Wq,Wk -> wqk[512][256]
    int idx8 = (blk - 2048) * 256 + tid;
    int r = idx8 >> 5, c = (idx8 & 31) * 8;
    const float* src = (r < 256) ? (Wq + (size_t)r * 256 + c)
                                 : (Wk + (size_t)(r - 256) * 256 + c);
    float4 v0 = *(const float4*)(src);
    float4 v1 = *(const float4*)(src + 4);
    short8 o;
    o[0] = f2bf(v0.x); o[1] = f2bf(v0.y); o[2] = f2bf(v0.z); o[3] = f2bf(v0.w);
    o[4] = f2bf(v1.x); o[5] = f2bf(v1.y); o[6] = f2bf(v1.z); o[7] = f2bf(v1.w);
    *(short8*)(wqk + (size_t)idx8 * 8) = o;
  } else if (blk < 2216) {
    // Wa,Wm -> [416][64], zero-padded
    int idx = (blk - 2112) * 256 + tid;
    int r = idx >> 6, c = idx & 63;
    float va = 0.f, vm = 0.f;
    if (r < 400 && c < 50) { va = Wa[r * 50 + c]; vm = Wm[r * 50 + c]; }
    wab[idx] = f2bf(va); wmb[idx] = f2bf(vm);
  } else {
    // zero q/k slack rows (819200..819263) so last-bh padded reads are finite
    short8 z = (short8){0,0,0,0,0,0,0,0};
    *(short8*)(qws + (size_t)819200 * 32 + tid * 8) = z;
    *(short8*)(kws + (size_t)819200 * 32 + tid * 8) = z;
  }
}

// ---------------- projection GEMM ----------------
__global__ __launch_bounds__(256) void proj_kernel(
    const float* __restrict__ x, const u16* __restrict__ wqk,
    const float* __restrict__ bq, const float* __restrict__ bk,
    u16* __restrict__ qws, u16* __restrict__ kws) {
  __shared__ char xa[64 * 512];
  __shared__ char wb[64 * 512];
  const int tid = threadIdx.x;
  const int m0 = blockIdx.x * 64;

#pragma unroll
  for (int t = 0; t < 16; ++t) {
    int idx = tid + t * 256;
    int r = idx >> 6, c4 = idx & 63;
    float4 v = *(const float4*)(x + (size_t)(m0 + r) * 256 + c4 * 4);
    unsigned long long pk = (unsigned long long)f2bf(v.x)
                          | ((unsigned long long)f2bf(v.y) << 16)
                          | ((unsigned long long)f2bf(v.z) << 32)
                          | ((unsigned long long)f2bf(v.w) << 48);
    int byte = (r * 512 + c4 * 8) ^ ((r & 7) << 4);
    *(unsigned long long*)(xa + byte) = pk;
  }
  __syncthreads();

  const int w = tid >> 6, l = tid & 63, lo = l & 15, g = l >> 4;
  short8 a[8];
  const int ra = 16 * w + lo;
#pragma unroll
  for (int ks = 0; ks < 8; ++ks)
    a[ks] = *(const short8*)(xa + ((ra * 512 + ks * 64 + g * 16) ^ ((ra & 7) << 4)));
  size_t mb[4];
#pragma unroll
  for (int i = 0; i < 4; ++i) {
    int m = m0 + 16 * w + 4 * g + i;
    int b = m / 50;
    int n = m - 50 * b;
    mb[i] = (size_t)b * 12800 + (size_t)n * 32;
  }

  for (int nt = 0; nt < 8; ++nt) {
    __syncthreads();
#pragma unroll
    for (int t = 0; t < 8; ++t) {
      int idx = tid + t * 256;
      int r = idx >> 5, c8 = idx & 31;
      short8 v = *(const short8*)(wqk + (size_t)(nt * 64 + r) * 256 + c8 * 8);
      int byte = (r * 512 + c8 * 16) ^ ((r & 7) << 4);
      *(short8*)(wb + byte) = v;
    }
    __syncthreads();

    f32x4 acc[4];
#pragma unroll
    for (int tj = 0; tj < 4; ++tj) acc[tj] = (f32x4){0.f, 0.f, 0.f, 0.f};
#pragma unroll
    for (int ks = 0; ks < 8; ++ks) {
#pragma unroll
      for (int tj = 0; tj < 4; ++tj) {
        int rb = 16 * tj + lo;
        short8 bb = *(const short8*)(wb + ((rb * 512 + ks * 64 + g * 16) ^ ((rb & 7) << 4)));
        acc[tj] = __builtin_amdgcn_mfma_f32_16x16x32_bf16(a[ks], bb, acc[tj], 0, 0, 0);
      }
    }
    const int n0 = nt * 64;
#pragma unroll
    for (int tj = 0; tj < 4; ++tj) {
      int j = n0 + 16 * tj + lo;
      int jj = j & 255;
      float bias = (j < 256) ? bq[jj] : bk[jj];
      u16* dst = (j < 256) ? qws : kws;
      int hh = jj >> 5, d = jj & 31;
#pragma unroll
      for (int i = 0; i < 4; ++i)
        dst[mb[i] + (size_t)hh * 1600 + d] = f2bf(acc[tj][i] + bias);
    }
  }
}

// ---------------- fused attention ----------------
// Per softmax tile tj: exp2(fma) -> tree-sum -> scale -> pack -> 16-row P
// (double-buffered) -> fence -> 2 b128 reads -> 4 PV MFMAs into O[tj].
__device__ __forceinline__ void sm_pv_tile(
    f32x4 (&S)[4], const float (&bml)[4][4], float sl2e, float lam,
    u16* pb, const short8 (&vb)[2][2], f32x4 (&Otj)[2], int tj, int lo, int g) {
  float p[4][4];
#pragma unroll
  for (int ti = 0; ti < 4; ++ti)
#pragma unroll
    for (int i = 0; i < 4; ++i)
      p[ti][i] = exp2_fast(S[ti][i] * sl2e + bml[ti][i]);
  float t0 = (p[0][0] + p[0][1]) + (p[0][2] + p[0][3]);
  float t1 = (p[1][0] + p[1][1]) + (p[1][2] + p[1][3]);
  float t2 = (p[2][0] + p[2][1]) + (p[2][2] + p[2][3]);
  float t3 = (p[3][0] + p[3][1]) + (p[3][2] + p[3][3]);
  float sum = (t0 + t1) + (t2 + t3);
  sum += __shfl_xor(sum, 16);
  sum += __shfl_xor(sum, 32);
  float r = lam * __builtin_amdgcn_rcpf(sum);
  u16* base = pb + (tj & 1) * 1152 + lo * 72;
#pragma unroll
  for (int ti = 0; ti < 4; ++ti) {
    uint2 pk;
    pk.x = cvt_pk_bf16(p[ti][0] * r, p[ti][1] * r);
    pk.y = cvt_pk_bf16(p[ti][2] * r, p[ti][3] * r);
    *(uint2*)(base + 16 * ti + 4 * g) = pk;
  }
  lds_fence();   // all 64 lanes' P writes complete before fragment reads
#pragma unroll
  for (int ks = 0; ks < 2; ++ks) {
    short8 pa = *(const short8*)(pb + (tj & 1) * 1152 + lo * 72 + ks * 32 + g * 8);
#pragma unroll
    for (int tjv = 0; tjv < 2; ++tjv)
      Otj[tjv] = __builtin_amdgcn_mfma_f32_16x16x32_bf16(pa, vb[tjv][ks], Otj[tjv], 0, 0, 0);
  }
}

__device__ __forceinline__ void adj_phase(
    const u16* __restrict__ aBase, const u16* __restrict__ bBase,
    const float* __restrict__ biasPtr, float lam,
    u16* pb, const short8 (&vb)[2][2], f32x4 (&O)[4][2], int lo, int g) {
  short8 af[4][2];
#pragma unroll
  for (int ti = 0; ti < 4; ++ti)
#pragma unroll
    for (int ks = 0; ks < 2; ++ks)
      af[ti][ks] = *(const short8*)(aBase + (size_t)(lo + 16 * ti) * 64 + ks * 32 + g * 8);
  float bml[4][4];
#pragma unroll
  for (int ti = 0; ti < 4; ++ti)
#pragma unroll
    for (int i = 0; i < 4; ++i) {
      int m = 16 * ti + 4 * g + i;
      bml[ti][i] = (m < 50) ? biasPtr[m] * L2E : -1.0e30f;
    }
#pragma unroll
  for (int tj = 0; tj < 4; ++tj) {
    short8 bf0 = *(const short8*)(bBase + (size_t)(lo + 16 * tj) * 64 + g * 8);
    short8 bf1 = *(const short8*)(bBase + (size_t)(lo + 16 * tj) * 64 + 32 + g * 8);
    f32x4 S[4];
#pragma unroll
    for (int ti = 0; ti < 4; ++ti) S[ti] = (f32x4){0.f, 0.f, 0.f, 0.f};
#pragma unroll
    for (int ti = 0; ti < 4; ++ti)
      S[ti] = __builtin_amdgcn_mfma_f32_16x16x32_bf16(af[ti][0], bf0, S[ti], 0, 0, 0);
#pragma unroll
    for (int ti = 0; ti < 4; ++ti)
      S[ti] = __builtin_amdgcn_mfma_f32_16x16x32_bf16(af[ti][1], bf1, S[ti], 0, 0, 0);
    sm_pv_tile(S, bml, L2E, lam, pb, vb, O[tj], tj, lo, g);
  }
}

__global__ __launch_bounds__(256) void attn_kernel(
    const u16* __restrict__ qws, const u16* __restrict__ kws,
    const u16* __restrict__ adjb, const u16* __restrict__ matb,
    const u16* __restrict__ wab, const u16* __restrict__ wmb,
    const float* __restrict__ ba, const float* __restrict__ bm,
    const float* __restrict__ lambdas, float* __restrict__ out) {
  __shared__ u16 smem[4][2304];          // per wave 4608B: kT[32][72] then P dbuf
  const int tid = threadIdx.x;
  const int w = tid >> 6, l = tid & 63, lo = l & 15, g = l >> 4;
  const int bh = blockIdx.x * 4 + w;
  const int b = bh >> 3, h = bh & 7;
  u16* sh = smem[w];

  float la = lambdas[h * 3 + 0], lb = lambdas[h * 3 + 1], lc = lambdas[h * 3 + 2];
  float lmx = fmaxf(la, fmaxf(lb, lc));
  float e0 = __expf(la - lmx), e1 = __expf(lb - lmx), e2 = __expf(lc - lmx);
  float einv = 1.f / (e0 + e1 + e2);
  float lam0 = e0 * einv, lam1 = e1 * einv, lam2 = e2 * einv;

  // stage kT = V^T [32 d][72 m], zero pad m>=50
  {
    const u16* kr = kws + (size_t)bh * 1600 + (size_t)l * 32;
#pragma unroll
    for (int ch = 0; ch < 4; ++ch) {
      short8 v = (short8){0, 0, 0, 0, 0, 0, 0, 0};
      if (l < 50) v = *(const short8*)(kr + ch * 8);
#pragma unroll
      for (int jj = 0; jj < 8; ++jj)
        sh[(ch * 8 + jj) * 72 + l] = (u16)v[jj];
    }
  }
  lds_fence();
  short8 vb[2][2];
#pragma unroll
  for (int tjv = 0; tjv < 2; ++tjv)
#pragma unroll
    for (int ks = 0; ks < 2; ++ks)
      vb[tjv][ks] = *(const short8*)(sh + (lo + 16 * tjv) * 72 + ks * 32 + g * 8);

  f32x4 O[4][2];
#pragma unroll
  for (int ti = 0; ti < 4; ++ti)
#pragma unroll
    for (int tjv = 0; tjv < 2; ++tjv) O[ti][tjv] = (f32x4){0.f, 0.f, 0.f, 0.f};

  // ---- phase 1: S^T = K·Q^T, scale C^-0.5 = 1/16 (folded with log2e) ----
  {
    short8 af[4];
#pragma unroll
    for (int ti = 0; ti < 4; ++ti)
      af[ti] = *(const short8*)(kws + (size_t)bh * 1600 + (size_t)(lo + 16 * ti) * 32 + g * 8);
    float bml[4][4];
#pragma unroll
    for (int ti = 0; ti < 4; ++ti)
#pragma unroll
      for (int i = 0; i < 4; ++i)
        bml[ti][i] = (16 * ti + 4 * g + i < 50) ? 0.f : -1.0e30f;
#pragma unroll
    for (int tj = 0; tj < 4; ++tj) {
      short8 qf = *(const short8*)(qws + (size_t)bh * 1600 + (size_t)(lo + 16 * tj) * 32 + g * 8);
      f32x4 S[4];
#pragma unroll
      for (int ti = 0; ti < 4; ++ti) S[ti] = (f32x4){0.f, 0.f, 0.f, 0.f};
#pragma unroll
      for (int ti = 0; ti < 4; ++ti)
        S[ti] = __builtin_amdgcn_mfma_f32_16x16x32_bf16(af[ti], qf, S[ti], 0, 0, 0);
      sm_pv_tile(S, bml, 0.0625f * L2E, lam0, sh, vb, O[tj], tj, lo, g);
    }
  }
  // ---- phases 2 & 3 ----
  adj_phase(wab + (size_t)h * 3200, adjb + (size_t)b * 3200, ba + h * 50,
            lam1, sh, vb, O, lo, g);
  adj_phase(wmb + (size_t)h * 3200, matb + (size_t)b * 3200, bm + h * 50,
            lam2, sh, vb, O, lo, g);

  // out[b][n][h*32+d], f32
  float* ob = out + ((size_t)b * 50) * 256 + h * 32;
#pragma unroll
  for (int ti = 0; ti < 4; ++ti)
#pragma unroll
    for (int i = 0; i < 4; ++i) {
      int n = 16 * ti + 4 * g + i;
      if (n < 50) {
#pragma unroll
        for (int tjv = 0; tjv < 2; ++tjv)
          ob[(size_t)n * 256 + 16 * tjv + lo] = O[ti][tjv][i];
      }
    }
}

extern "C" void kernel_launch(void* const* d_in, const int* in_sizes, int n_in,
                              void* d_out, int out_size, void* d_ws, size_t ws_size,
                              hipStream_t stream) {
  const float* x       = (const float*)d_in[0];
  const float* adj     = (const float*)d_in[1];
  const float* mat     = (const float*)d_in[2];
  const float* Wq      = (const float*)d_in[3];
  const float* bq      = (const float*)d_in[4];
  const float* Wk      = (const float*)d_in[5];
  const float* bk      = (const float*)d_in[6];
  const float* Wa      = (const float*)d_in[7];
  const float* ba      = (const float*)d_in[8];
  const float* Wm      = (const float*)d_in[9];
  const float* bm      = (const float*)d_in[10];
  const float* lambdas = (const float*)d_in[11];
  float* out = (float*)d_out;

  char* ws = (char*)d_ws;
  u16* wqk  = (u16*)ws; ws += (size_t)512 * 256 * 2;
  u16* wab  = (u16*)ws; ws += (size_t)416 * 64 * 2;
  u16* wmb  = (u16*)ws; ws += (size_t)416 * 64 * 2;
  u16* adjb = (u16*)ws; ws += (size_t)102416 * 64 * 2;
  u16* matb = (u16*)ws; ws += (size_t)102416 * 64 * 2;
  u16* qws  = (u16*)ws; ws += (size_t)819264 * 32 * 2;   // 16384*50 + 64 slack rows
  u16* kws  = (u16*)ws; ws += (size_t)819264 * 32 * 2;

  cast_all<<<2217, 256, 0, stream>>>(adj, mat, Wq, Wk, Wa, Wm,
                                     adjb, matb, wqk, wab, wmb, qws, kws);
  proj_kernel<<<1600, 256, 0, stream>>>(x, wqk, bq, bk, qws, kws);
  attn_kernel<<<4096, 256, 0, stream>>>(qws, kws, adjb, matb, wab, wmb, ba, bm, lambdas, out);
}